// Round 14
// baseline (546.830 us; speedup 1.0000x reference)
//
#include <hip/hip_runtime.h>

#define N_ROWS 32768
#define DIM    256
#define NE     256
#define KP     4096
#define NQ     4
#define ND     8388608   // N_ROWS*DIM
#define RESCORE_MARGIN 2e-4f

typedef short short8 __attribute__((ext_vector_type(8)));
typedef unsigned short ushort8v __attribute__((ext_vector_type(8)));
typedef float f32x4  __attribute__((ext_vector_type(4)));

__device__ inline float bf2f(unsigned short u) {
  return __uint_as_float(((unsigned)u) << 16);
}
__device__ inline unsigned short f2bf(float f) {
  unsigned u = __float_as_uint(f);
  u += 0x7fffu + ((u >> 16) & 1u);
  return (unsigned short)(u >> 16);
}
// Raw v_exp_f32: args in [-29, 0] -> normal results; OCML's denormal-safe
// sequence is pure overhead (measured: removed ~10us/dispatch in r8).
__device__ inline float fexp2(float x) { return __builtin_amdgcn_exp2f(x); }

// Fragment-major packed layout (16B chunks): chunk (tile*8+f)*64 + quad*16 + l16
// holds row tile*16+l16, dims [f*32+quad*8, +8). For row r, dim chunk j (=k/8):
// index ((r>>4)*8 + (j>>2))*64 + ((j&3)<<4) + (r&15).
__device__ inline size_t chunkIdx(int row, int j) {
  return (size_t)(((row >> 4) * 8 + (j >> 2)) * 64 + ((j & 3) << 4) + (row & 15));
}

// ---------------- stage 0 prep: packed Xn/rH/rL, rnorm (16 rows/block,
// coalesced reads + LDS transpose + coalesced 1KB packed stores) ----------------
__global__ __launch_bounds__(256) void prep0_kernel(
    const float* __restrict__ x,
    unsigned short* __restrict__ Xnp, float* __restrict__ rnorm,
    unsigned short* __restrict__ rHp, unsigned short* __restrict__ rLp) {
  __shared__ float ldsNr[16 * 260];
  __shared__ float ssl[16];
  const int tid = threadIdx.x, wave = tid >> 6, lane = tid & 63;
  const int t = blockIdx.x;  // grid 2048, one packed tile (16 rows)
#pragma unroll
  for (int rr = 0; rr < 4; ++rr) {
    const int rl = wave * 4 + rr;
    const int row = t * 16 + rl;
    float4 v = ((const float4*)(x + (size_t)row * DIM))[lane];
    float ss = v.x * v.x + v.y * v.y + v.z * v.z + v.w * v.w;
#pragma unroll
    for (int m = 1; m < 64; m <<= 1) ss += __shfl_xor(ss, m, 64);
    *(float4*)(&ldsNr[rl * 260 + lane * 4]) = v;
    if (lane == 0) { ssl[rl] = ss; rnorm[row] = ss; }
  }
  __syncthreads();
  const int l16 = lane & 15, quad = lane >> 4;
  const float sc = rsqrtf(ssl[l16] + 1e-12f);
#pragma unroll
  for (int ff = 0; ff < 2; ++ff) {
    const int f = wave * 2 + ff;
    const float* p = &ldsNr[l16 * 260 + f * 32 + quad * 8];
    float4 u0 = *(const float4*)(p);
    float4 u1 = *(const float4*)(p + 4);
    float vv[8] = {u0.x, u0.y, u0.z, u0.w, u1.x, u1.y, u1.z, u1.w};
    ushort8v h, l, xn;
#pragma unroll
    for (int u = 0; u < 8; ++u) {
      h[u] = f2bf(vv[u]); l[u] = f2bf(vv[u] - bf2f(h[u])); xn[u] = f2bf(vv[u] * sc);
    }
    const size_t c = ((size_t)(t * 8 + f) * 64 + lane) * 8;
    *(ushort8v*)(rHp + c) = h;
    *(ushort8v*)(rLp + c) = l;
    *(ushort8v*)(Xnp + c) = xn;
  }
}

// ---------------- all codebook row norms (NQ*NE rows), once ----------------
__global__ __launch_bounds__(256) void cbnorm_kernel(
    const float* __restrict__ cb, float* __restrict__ cbn) {
  const int wave = threadIdx.x >> 6, lane = threadIdx.x & 63;
  const int e = blockIdx.x * 4 + wave;  // 0..NQ*NE-1
  float4 v = ((const float4*)(cb + (size_t)e * DIM))[lane];
  float ss = v.x * v.x + v.y * v.y + v.z * v.z + v.w * v.w;
#pragma unroll
  for (int m = 1; m < 64; m <<= 1) ss += __shfl_xor(ss, m, 64);
  if (lane == 0) cbn[e] = ss;
}

// ---------------- codebook hi/lo split, packed, all stages, once ----------------
__global__ __launch_bounds__(256) void cbsplit_kernel(
    const float* __restrict__ cb, unsigned short* __restrict__ cbHp,
    unsigned short* __restrict__ cbLp) {
  const int p = blockIdx.x * 256 + threadIdx.x;  // grid 128 -> 32768 chunks
  const int stage = p >> 13, ps = p & 8191;
  const int l16 = ps & 15, quad = (ps >> 4) & 3, kf = (ps >> 6) & 7, et = ps >> 9;
  const int e = et * 16 + l16, k0 = kf * 32 + quad * 8;
  const float* src = cb + ((size_t)(stage * NE + e)) * DIM + k0;
  float4 v0 = ((const float4*)src)[0], v1 = ((const float4*)src)[1];
  float vv[8] = {v0.x, v0.y, v0.z, v0.w, v1.x, v1.y, v1.z, v1.w};
  ushort8v h, l;
#pragma unroll
  for (int i = 0; i < 8; ++i) {
    h[i] = f2bf(vv[i]); l[i] = f2bf(vv[i] - bf2f(h[i]));
  }
  *(ushort8v*)(cbHp + (size_t)p * 8) = h;
  *(ushort8v*)(cbLp + (size_t)p * 8) = l;
}

// ---------------- per-stage: gather xn[i1] (packed Qg) + pos, MERGED with
// lse_final of the previous stage (saves 3 launches/run).
// blocks 0..1023: gather for stage q, writes posCur.
// blocks 1024..1039: if q>0, lse for stage q-1 (reads ssum + posPrev, adds to
// acc[4+q-1]) then RE-ZEROES ssum in place for stage q's sim accumulation.
// pos is double-buffered so gather(q) writes never race lse(q-1) reads;
// ssum stage-0 zeroing is a one-time memset in kernel_launch.
__global__ __launch_bounds__(256) void gather_lse_kernel(
    const unsigned short* __restrict__ Xnp, const int* __restrict__ i1,
    const int* __restrict__ i2, unsigned short* __restrict__ Qgp,
    float* __restrict__ posCur, const float* __restrict__ posPrev,
    float* __restrict__ ssum, float* __restrict__ acc, int stage) {
  if (blockIdx.x >= 1024) {
    const int t = threadIdx.x;
    const int k = (blockIdx.x - 1024) * 256 + t;
    if (stage > 0) {
      float v = 10.0f + __logf(ssum[k]) - posPrev[k];
#pragma unroll
      for (int m = 1; m < 64; m <<= 1) v += __shfl_xor(v, m, 64);
      __shared__ float red[4];
      if ((t & 63) == 0) red[t >> 6] = v;
      __syncthreads();
      if (t == 0) atomicAdd(&acc[4 + stage - 1], red[0] + red[1] + red[2] + red[3]);
      ssum[k] = 0.0f;  // ready for this stage's sim
    }
    return;
  }
  const int wave = threadIdx.x >> 6, lane = threadIdx.x & 63;
  const int k = blockIdx.x * 4 + wave;
  const int a = i1[k], b = i2[k];
  const int j2 = lane >> 1, off = (lane & 1) * 4;
  ushort4 va = *(const ushort4*)(Xnp + chunkIdx(a, j2) * 8 + off);
  ushort4 vb = *(const ushort4*)(Xnp + chunkIdx(b, j2) * 8 + off);
  *(ushort4*)(Qgp + chunkIdx(k, j2) * 8 + off) = va;
  float d = bf2f(va.x) * bf2f(vb.x) + bf2f(va.y) * bf2f(vb.y) +
            bf2f(va.z) * bf2f(vb.z) + bf2f(va.w) * bf2f(vb.w);
#pragma unroll
  for (int m = 1; m < 64; m <<= 1) d += __shfl_xor(d, m, 64);
  if (lane == 0) posCur[k] = d * 10.0f;  // /TEMP
}

// ================== co-scheduled sim + (argmin+update) ==================
// Independent except Xnp (double-buffered: sim reads cur, tail writes next).
// r14 LJF dispatch map: blocks g<2048 = mixed zone, 1:1 sim/argmin via the
// XCD-decorrelated XOR map (type=(g^(g>>3))&1, per-16-window rank
// ((m>>3)<<2)|((m&7)>>1), both bijective -- r12-verified); g>=2048 = pure sim
// (slots 1024..2047). All 1024 argmin blocks (the LONG type, ~32us vs sim
// ~24us) are dispatched in the first 2/3; the tail drains with uniform short
// sim blocks (longest-job-first). Steady-state per-CU heterogeneous mix is
// preserved -> co-scheduling benefit kept (r10: fused 101 vs 134 serial).
// s_setprio(1) wraps sim's MFMA cluster (role-split regime; measured
// 124->117us in r13).

__device__ __forceinline__ void sim_body(
    int sid, unsigned short* ldsB,
    const unsigned short* __restrict__ Qgp,
    const unsigned short* __restrict__ Xnp,
    float* __restrict__ s_sum) {
  const int tid  = threadIdx.x;
  const int lane = tid & 63;
  const int wave = tid >> 6;
  const int quad = lane >> 4;
  const int l16  = lane & 15;
  const int bx = sid & 31;   // q-tile group 0..31
  const int by = sid >> 5;   // n-chunk 0..63

  const int qt0  = bx * 8 + wave * 2;
  const int qbase = bx * 128 + wave * 32;

  short8 a[2][8];
#pragma unroll
  for (int t = 0; t < 2; ++t)
#pragma unroll
    for (int f = 0; f < 8; ++f)
      a[t][f] = *(const short8*)(Qgp + ((size_t)(((qt0 + t) * 8 + f) * 64 + lane)) * 8);

  float s[2][4] = {};
  const float C1 = 14.4269504088896341f;  // 10*log2(e); exp(10d-10)=exp2(d*C1-C1)
  const unsigned short* bsrc = Xnp + (size_t)(by * 32) * 4096;

  auto stageB = [&](int g) {
    const unsigned short* src = bsrc + (size_t)g * 4096 + wave * 1024 + lane * 8;
#pragma unroll
    for (int p = 0; p < 2; ++p)
      __builtin_amdgcn_global_load_lds(
          (const __attribute__((address_space(1))) unsigned int*)(src + p * 512),
          (__attribute__((address_space(3))) unsigned int*)(&ldsB[wave * 1024 + p * 512]),
          16, 0, 0);
  };

  stageB(0);
  for (int g = 0; g < 32; ++g) {
    asm volatile("s_waitcnt vmcnt(0)" ::: "memory");
    __builtin_amdgcn_s_barrier();
    __builtin_amdgcn_sched_barrier(0);
    short8 b[8];
#pragma unroll
    for (int f = 0; f < 8; ++f)
      b[f] = *(const short8*)(&ldsB[f * 512 + lane * 8]);
    asm volatile("s_waitcnt lgkmcnt(0)" ::: "memory");
    __builtin_amdgcn_s_barrier();
    __builtin_amdgcn_sched_barrier(0);
    if (g + 1 < 32) stageB(g + 1);

    f32x4 acc0[2] = {{0.f, 0.f, 0.f, 0.f}, {0.f, 0.f, 0.f, 0.f}};
    f32x4 acc1[2] = {{0.f, 0.f, 0.f, 0.f}, {0.f, 0.f, 0.f, 0.f}};
    __builtin_amdgcn_s_setprio(1);
#pragma unroll
    for (int f = 0; f < 4; ++f)
#pragma unroll
      for (int t = 0; t < 2; ++t) {
        acc0[t] = __builtin_amdgcn_mfma_f32_16x16x32_bf16(a[t][f], b[f], acc0[t], 0, 0, 0);
        acc1[t] = __builtin_amdgcn_mfma_f32_16x16x32_bf16(a[t][f + 4], b[f + 4], acc1[t], 0, 0, 0);
      }
    __builtin_amdgcn_s_setprio(0);
#pragma unroll
    for (int t = 0; t < 2; ++t) {
      f32x4 m = acc0[t] + acc1[t];
#pragma unroll
      for (int i = 0; i < 4; ++i)
        s[t][i] += fexp2(fmaf(m[i], C1, -C1));
    }
  }
#pragma unroll
  for (int m = 1; m < 16; m <<= 1)
#pragma unroll
    for (int t = 0; t < 2; ++t)
#pragma unroll
      for (int i = 0; i < 4; ++i) s[t][i] += __shfl_xor(s[t][i], m, 64);
  if (l16 == 0) {
#pragma unroll
    for (int t = 0; t < 2; ++t)
#pragma unroll
      for (int i = 0; i < 4; ++i)
        atomicAdd(&s_sum[qbase + t * 16 + quad * 4 + i], s[t][i]);
  }
}

// 32 rows/block (aid in [0,1024)); GEMM + top-2 + rescore + fused update tail.
__device__ __forceinline__ void argmin_update_body(
    int aid, char* smem,
    const float* __restrict__ xin, float* __restrict__ resid,
    const float* __restrict__ cb,
    const unsigned short* __restrict__ cbHp, const unsigned short* __restrict__ cbLp,
    const float* __restrict__ cbn, float* __restrict__ rnorm,
    unsigned short* __restrict__ rHp, unsigned short* __restrict__ rLp,
    unsigned short* __restrict__ XnpN,
    float* __restrict__ xq, float* __restrict__ idxf, float* __restrict__ acc,
    int stage) {
  float (*sV1)[32] = (float(*)[32])(smem);
  float (*sV2)[32] = (float(*)[32])(smem + 512);
  int   (*sIx)[32] = (int(*)[32])(smem + 1024);
  int*   sIdx      = (int*)(smem + 1536);
  int*   sFlag     = (int*)(smem + 1664);
  float* sred      = (float*)(smem + 1792);
  const int tid  = threadIdx.x;
  const int lane = tid & 63;
  const int wave = tid >> 6;
  const int quad = lane >> 4;
  const int l16  = lane & 15;
  const int rbase = aid * 32;
  const int t0 = aid * 2;
  const float* __restrict__ src = (stage == 0) ? xin : resid;

  f32x4 acc4[2][4];
#pragma unroll
  for (int rt = 0; rt < 2; ++rt)
#pragma unroll
    for (int ct = 0; ct < 4; ++ct) acc4[rt][ct] = (f32x4){0.f, 0.f, 0.f, 0.f};

  auto loadA = [&](int kf, short8 (&aH)[2], short8 (&aL)[2]) {
#pragma unroll
    for (int rt = 0; rt < 2; ++rt) {
      const size_t off = ((size_t)(((t0 + rt) * 8 + kf) * 64 + lane)) * 8;
      aH[rt] = *(const short8*)(rHp + off);
      aL[rt] = *(const short8*)(rLp + off);
    }
  };
  auto loadBc = [&](int kf, short8 (&bH)[4], short8 (&bL)[4]) {
#pragma unroll
    for (int ct = 0; ct < 4; ++ct) {
      const size_t boff = ((size_t)(((wave * 4 + ct) * 8 + kf) * 64 + lane)) * 8;
      bH[ct] = *(const short8*)(cbHp + boff);
      bL[ct] = *(const short8*)(cbLp + boff);
    }
  };
  auto computeK = [&](short8 (&aH)[2], short8 (&aL)[2], short8 (&bH)[4],
                      short8 (&bL)[4]) {
#pragma unroll
    for (int ct = 0; ct < 4; ++ct)
#pragma unroll
      for (int rt = 0; rt < 2; ++rt) {
        acc4[rt][ct] = __builtin_amdgcn_mfma_f32_16x16x32_bf16(aL[rt], bH[ct], acc4[rt][ct], 0, 0, 0);
        acc4[rt][ct] = __builtin_amdgcn_mfma_f32_16x16x32_bf16(aH[rt], bL[ct], acc4[rt][ct], 0, 0, 0);
        acc4[rt][ct] = __builtin_amdgcn_mfma_f32_16x16x32_bf16(aH[rt], bH[ct], acc4[rt][ct], 0, 0, 0);
      }
  };

  short8 aH0[2], aL0[2], bH0[4], bL0[4], aH1[2], aL1[2], bH1[4], bL1[4];
  loadA(0, aH0, aL0); loadBc(0, bH0, bL0);
  for (int kf = 0; kf < 8; kf += 2) {
    loadA(kf + 1, aH1, aL1); loadBc(kf + 1, bH1, bL1);
    computeK(aH0, aL0, bH0, bL0);
    if (kf + 2 < 8) { loadA(kf + 2, aH0, aL0); loadBc(kf + 2, bH0, bL0); }
    computeK(aH1, aL1, bH1, bL1);
  }

  // ---- epilogue: per-row top-2 over this wave's 64 e ----
  float cbe[4];
#pragma unroll
  for (int ct = 0; ct < 4; ++ct) cbe[ct] = cbn[(wave * 4 + ct) * 16 + l16];
#pragma unroll
  for (int rt = 0; rt < 2; ++rt) {
    float b1[4], b2[4]; int e1[4];
#pragma unroll
    for (int i = 0; i < 4; ++i) { b1[i] = 3.4e38f; b2[i] = 3.4e38f; e1[i] = 0; }
#pragma unroll
    for (int ct = 0; ct < 4; ++ct) {
      const int e = (wave * 4 + ct) * 16 + l16;
#pragma unroll
      for (int i = 0; i < 4; ++i) {
        const float v = fmaf(-2.0f, acc4[rt][ct][i], cbe[ct]);
        if (v < b1[i]) { b2[i] = b1[i]; b1[i] = v; e1[i] = e; }
        else if (v < b2[i]) b2[i] = v;
      }
    }
#pragma unroll
    for (int m = 1; m < 16; m <<= 1) {
#pragma unroll
      for (int i = 0; i < 4; ++i) {
        const float o1 = __shfl_xor(b1[i], m, 64);
        const float o2 = __shfl_xor(b2[i], m, 64);
        const int   oe = __shfl_xor(e1[i], m, 64);
        if (o1 < b1[i] || (o1 == b1[i] && oe < e1[i])) {
          b2[i] = fminf(b1[i], o2); b1[i] = o1; e1[i] = oe;
        } else {
          b2[i] = fminf(b2[i], o1);
        }
      }
    }
    if (l16 == 0) {
#pragma unroll
      for (int i = 0; i < 4; ++i) {
        const int r = rt * 16 + quad * 4 + i;
        sV1[wave][r] = b1[i]; sV2[wave][r] = b2[i]; sIx[wave][r] = e1[i];
      }
    }
  }
  __syncthreads();
  if (tid < 32) {
    float v1 = 3.4e38f, v2 = 3.4e38f; int ix = 0;
#pragma unroll
    for (int w = 0; w < 4; ++w) {
      const float a1 = sV1[w][tid], a2 = sV2[w][tid];
      const int ae = sIx[w][tid];
      if (a1 < v1) { v2 = fminf(v1, a2); v1 = a1; ix = ae; }
      else { v2 = fminf(v2, fminf(a1, a2)); }
    }
    sIdx[tid] = ix;
    sFlag[tid] = (v2 - v1 < RESCORE_MARGIN) ? 1 : 0;
  }
  __syncthreads();

  // ---- exact fp32 rescore for flagged rows (rare) ----
  for (int rr = 0; rr < 8; ++rr) {
    const int r = wave * 8 + rr;
    if (sFlag[r]) {
      const int row = rbase + r;
      const float* rrow = src + (size_t)row * DIM;
      float d[4] = {0.f, 0.f, 0.f, 0.f};
      for (int kb = 0; kb < 64; ++kb) {
        const float4 rv = ((const float4*)rrow)[kb];
#pragma unroll
        for (int j = 0; j < 4; ++j) {
          const float4 cv = ((const float4*)(cb + (size_t)(lane + 64 * j) * DIM))[kb];
          d[j] = fmaf(rv.x, cv.x, d[j]);
          d[j] = fmaf(rv.y, cv.y, d[j]);
          d[j] = fmaf(rv.z, cv.z, d[j]);
          d[j] = fmaf(rv.w, cv.w, d[j]);
        }
      }
      const float rn = rnorm[row];
      float bv = 3.4e38f; int be = 0;
#pragma unroll
      for (int j = 0; j < 4; ++j) {
        const int e = lane + 64 * j;
        const float v = (rn - 2.0f * d[j]) + cbn[e];
        if (v < bv) { bv = v; be = e; }
      }
#pragma unroll
      for (int m = 1; m < 64; m <<= 1) {
        const float vo = __shfl_xor(bv, m, 64);
        const int   eo = __shfl_xor(be, m, 64);
        if (vo < bv || (vo == bv && eo < be)) { bv = vo; be = eo; }
      }
      if (lane == 0) sIdx[r] = be;
    }
  }
  __syncthreads();

  // ---- fused update tail: 2 rows/wave x 4 passes (r8 structure) ----
  const int half = lane >> 5, j = lane & 31;
  float msum = 0.0f;
  for (int i = 0; i < 4; ++i) {
    const int rr = i * 8 + wave * 2 + half;
    const int row = rbase + rr;
    const int e = sIdx[rr];
    const float4* rp = (const float4*)(src + (size_t)row * DIM + j * 8);
    float4 r0 = rp[0], r1 = rp[1];
    const float4* qp = (const float4*)(cb + (size_t)e * DIM + j * 8);
    float4 q0 = qp[0], q1 = qp[1];
    float nr[8] = {r0.x - q0.x, r0.y - q0.y, r0.z - q0.z, r0.w - q0.w,
                   r1.x - q1.x, r1.y - q1.y, r1.z - q1.z, r1.w - q1.w};
    float ss = 0.f;
#pragma unroll
    for (int u = 0; u < 8; ++u) ss += nr[u] * nr[u];
    if (stage == 3) {
      // x_q = x - resid_final (xq never accumulated)
      const float4* xr = (const float4*)(xin + (size_t)row * DIM + j * 8);
      float4 x0 = xr[0], x1 = xr[1];
      float4* xp = (float4*)(xq + (size_t)row * DIM + j * 8);
      xp[0] = (float4){x0.x - nr[0], x0.y - nr[1], x0.z - nr[2], x0.w - nr[3]};
      xp[1] = (float4){x1.x - nr[4], x1.y - nr[5], x1.z - nr[6], x1.w - nr[7]};
    }
#pragma unroll
    for (int m = 1; m < 32; m <<= 1) ss += __shfl_xor(ss, m, 64);
    if (stage < 3) {
      float4* rw = (float4*)(resid + (size_t)row * DIM + j * 8);
      rw[0] = (float4){nr[0], nr[1], nr[2], nr[3]};
      rw[1] = (float4){nr[4], nr[5], nr[6], nr[7]};
      const float sc = rsqrtf(ss + 1e-12f);
      ushort8v h, l, xn;
#pragma unroll
      for (int u = 0; u < 8; ++u) {
        h[u] = f2bf(nr[u]); l[u] = f2bf(nr[u] - bf2f(h[u])); xn[u] = f2bf(nr[u] * sc);
      }
      const size_t c = chunkIdx(row, j) * 8;
      *(ushort8v*)(rHp + c) = h;
      *(ushort8v*)(rLp + c) = l;
      *(ushort8v*)(XnpN + c) = xn;   // NEXT-stage buffer (sim reads cur)
      if (j == 0) rnorm[row] = ss;
    }
    if (j == 0) {
      idxf[(size_t)row * NQ + stage] = (float)e;
      msum += ss;
    }
  }
  msum += __shfl_xor(msum, 32, 64);
  if (lane == 0) sred[wave] = msum;
  __syncthreads();
  if (tid == 0) atomicAdd(&acc[0], sred[0] + sred[1] + sred[2] + sred[3]);
}

__global__ __launch_bounds__(256, 2) void sim_argmin_kernel(
    const unsigned short* __restrict__ Qgp, const unsigned short* __restrict__ Xnp,
    float* __restrict__ s_sum,
    const float* __restrict__ xin, float* __restrict__ resid,
    const float* __restrict__ cb,
    const unsigned short* __restrict__ cbHp, const unsigned short* __restrict__ cbLp,
    const float* __restrict__ cbn, float* __restrict__ rnorm,
    unsigned short* __restrict__ rHp, unsigned short* __restrict__ rLp,
    unsigned short* __restrict__ XnpN,
    float* __restrict__ xq, float* __restrict__ idxf, float* __restrict__ acc,
    int stage) {
  __shared__ unsigned short smem[4096];  // 8KB: sim B-buffer / argmin scratch
  const int g = blockIdx.x;              // grid 3072
  int type, slot;
  if (g < 2048) {            // mixed zone: 1024 sim + 1024 argmin, XCD-balanced
    const int m = g & 15;
    type = (g ^ (g >> 3)) & 1;
    slot = (g >> 4) * 8 + (((m >> 3) << 2) | ((m & 7) >> 1));
  } else {                   // pure-sim tail (short blocks drain the dispatch)
    type = 0;
    slot = 1024 + (g - 2048);
  }
  if (type == 0) {
    sim_body(slot, smem, Qgp, Xnp, s_sum);
  } else {
    argmin_update_body(slot, (char*)smem, xin, resid, cb, cbHp, cbLp, cbn,
                       rnorm, rHp, rLp, XnpN, xq, idxf, acc, stage);
  }
}

// ---------------- last stage lse -> outer loss accumulator ----------------
__global__ __launch_bounds__(256) void lse_final_kernel(
    const float* __restrict__ s_sum, const float* __restrict__ pos,
    float* __restrict__ acc, int stage) {
  const int t = threadIdx.x;
  const int k = blockIdx.x * 256 + t;
  float v = 10.0f + __logf(s_sum[k]) - pos[k];
#pragma unroll
  for (int m = 1; m < 64; m <<= 1) v += __shfl_xor(v, m, 64);
  __shared__ float red[4];
  if ((t & 63) == 0) red[t >> 6] = v;
  __syncthreads();
  if (t == 0) atomicAdd(&acc[4 + stage], red[0] + red[1] + red[2] + red[3]);
}

// ---------------- finalize scalar outputs ----------------
__global__ void finalize_kernel(const float* __restrict__ acc, float* __restrict__ out) {
  const int t = threadIdx.x;
  if (t == 0) out[ND] = acc[0] * (1.25f / (4.0f * (float)ND));
  if (t < 4) out[ND + 1 + t] = acc[4 + t] * (1.0f / (float)KP);
}

extern "C" void kernel_launch(void* const* d_in, const int* in_sizes, int n_in,
                              void* d_out, int out_size, void* d_ws, size_t ws_size,
                              hipStream_t stream) {
  const float* x         = (const float*)d_in[0];
  const float* codebooks = (const float*)d_in[1];
  const int*   i1        = (const int*)d_in[2];
  const int*   i2        = (const int*)d_in[3];
  float* out = (float*)d_out;
  float* out_xq   = out;                 // [N, D]
  float* out_idxf = out + ND + 1 + NQ;   // [N, NQ] as float

  char* w = (char*)d_ws;
  float*          resid = (float*)w;          w += (size_t)N_ROWS * DIM * 4;
  unsigned short* XnpA  = (unsigned short*)w; w += (size_t)N_ROWS * DIM * 2;
  unsigned short* XnpB  = (unsigned short*)w; w += (size_t)N_ROWS * DIM * 2;
  unsigned short* rHp   = (unsigned short*)w; w += (size_t)N_ROWS * DIM * 2;
  unsigned short* rLp   = (unsigned short*)w; w += (size_t)N_ROWS * DIM * 2;
  float*          rnorm = (float*)w;          w += (size_t)N_ROWS * 4;
  unsigned short* Qgp   = (unsigned short*)w; w += (size_t)KP * DIM * 2;
  float*          posA  = (float*)w;          w += (size_t)KP * 4;
  float*          posB  = (float*)w;          w += (size_t)KP * 4;
  float*          ssum  = (float*)w;          w += (size_t)KP * 4;
  float*          cbn   = (float*)w;          w += (size_t)NQ * NE * 4;
  unsigned short* cbHp  = (unsigned short*)w; w += (size_t)NQ * NE * DIM * 2;
  unsigned short* cbLp  = (unsigned short*)w; w += (size_t)NQ * NE * DIM * 2;
  float*          acc   = (float*)w;          w += 32;  // [0]=sumsq, [4..7]=outer sums

  prep0_kernel<<<2048, 256, 0, stream>>>(x, XnpA, rnorm, rHp, rLp);
  cbnorm_kernel<<<256, 256, 0, stream>>>(codebooks, cbn);
  cbsplit_kernel<<<128, 256, 0, stream>>>(codebooks, cbHp, cbLp);
  hipMemsetAsync(acc, 0, 32, stream);
  hipMemsetAsync(ssum, 0, (size_t)KP * 4, stream);  // stage-0 zero; later
                                                    // stages re-zeroed by lse
  unsigned short* XnpCur = XnpA;
  unsigned short* XnpNxt = XnpB;
  float* pbuf[2] = {posA, posB};
  for (int q = 0; q < NQ; ++q) {
    const float* cb = codebooks + (size_t)q * NE * DIM;
    // gather(q) + lse(q-1); pos double-buffered (gather writes pbuf[q&1],
    // lse reads pbuf[(q-1)&1]); lse re-zeroes ssum after reading.
    gather_lse_kernel<<<1040, 256, 0, stream>>>(
        XnpCur, i1, i2, Qgp, pbuf[q & 1], pbuf[(q + 1) & 1], ssum, acc, q);
    sim_argmin_kernel<<<3072, 256, 0, stream>>>(
        Qgp, XnpCur, ssum, x, resid, cb,
        cbHp + (size_t)q * NE * DIM, cbLp + (size_t)q * NE * DIM,
        cbn + q * NE, rnorm, rHp, rLp, XnpNxt, out_xq, out_idxf, acc, q);
    unsigned short* tmp = XnpCur; XnpCur = XnpNxt; XnpNxt = tmp;
  }
  lse_final_kernel<<<16, 256, 0, stream>>>(ssum, pbuf[3 & 1], acc, 3);
  finalize_kernel<<<1, 64, 0, stream>>>(acc, out);
}

// Round 15
// 530.393 us; speedup vs baseline: 1.0310x; 1.0310x over previous
//
#include <hip/hip_runtime.h>

#define N_ROWS 32768
#define DIM    256
#define NE     256
#define KP     4096
#define NQ     4
#define ND     8388608   // N_ROWS*DIM
#define RESCORE_MARGIN 2e-4f

typedef short short8 __attribute__((ext_vector_type(8)));
typedef unsigned short ushort8v __attribute__((ext_vector_type(8)));
typedef float f32x4  __attribute__((ext_vector_type(4)));

__device__ inline float bf2f(unsigned short u) {
  return __uint_as_float(((unsigned)u) << 16);
}
__device__ inline unsigned short f2bf(float f) {
  unsigned u = __float_as_uint(f);
  u += 0x7fffu + ((u >> 16) & 1u);
  return (unsigned short)(u >> 16);
}
// Raw v_exp_f32: args in [-29, 0] -> normal results; OCML's denormal-safe
// sequence is pure overhead (measured: removed ~10us/dispatch in r8).
__device__ inline float fexp2(float x) { return __builtin_amdgcn_exp2f(x); }

// Fragment-major packed layout (16B chunks): chunk (tile*8+f)*64 + quad*16 + l16
// holds row tile*16+l16, dims [f*32+quad*8, +8). For row r, dim chunk j (=k/8):
// index ((r>>4)*8 + (j>>2))*64 + ((j&3)<<4) + (r&15).
__device__ inline size_t chunkIdx(int row, int j) {
  return (size_t)(((row >> 4) * 8 + (j >> 2)) * 64 + ((j & 3) << 4) + (row & 15));
}

// ================= fused init: prep0 (2048) | cbnorm (256) | cbsplit (128) ==
// The three init kernels are mutually independent (prep0 reads x; cbnorm and
// cbsplit read codebooks; all outputs disjoint) -- one launch, block-type
// dispatch, cbnorm/cbsplit overlap under prep0's memory time.

__device__ __forceinline__ void prep0_body(
    int t, float* ldsNr, float* ssl,
    const float* __restrict__ x,
    unsigned short* __restrict__ Xnp, float* __restrict__ rnorm,
    unsigned short* __restrict__ rHp, unsigned short* __restrict__ rLp) {
  const int tid = threadIdx.x, wave = tid >> 6, lane = tid & 63;
#pragma unroll
  for (int rr = 0; rr < 4; ++rr) {
    const int rl = wave * 4 + rr;
    const int row = t * 16 + rl;
    float4 v = ((const float4*)(x + (size_t)row * DIM))[lane];
    float ss = v.x * v.x + v.y * v.y + v.z * v.z + v.w * v.w;
#pragma unroll
    for (int m = 1; m < 64; m <<= 1) ss += __shfl_xor(ss, m, 64);
    *(float4*)(&ldsNr[rl * 260 + lane * 4]) = v;
    if (lane == 0) { ssl[rl] = ss; rnorm[row] = ss; }
  }
  __syncthreads();
  const int l16 = lane & 15, quad = lane >> 4;
  const float sc = rsqrtf(ssl[l16] + 1e-12f);
#pragma unroll
  for (int ff = 0; ff < 2; ++ff) {
    const int f = wave * 2 + ff;
    const float* p = &ldsNr[l16 * 260 + f * 32 + quad * 8];
    float4 u0 = *(const float4*)(p);
    float4 u1 = *(const float4*)(p + 4);
    float vv[8] = {u0.x, u0.y, u0.z, u0.w, u1.x, u1.y, u1.z, u1.w};
    ushort8v h, l, xn;
#pragma unroll
    for (int u = 0; u < 8; ++u) {
      h[u] = f2bf(vv[u]); l[u] = f2bf(vv[u] - bf2f(h[u])); xn[u] = f2bf(vv[u] * sc);
    }
    const size_t c = ((size_t)(t * 8 + f) * 64 + lane) * 8;
    *(ushort8v*)(rHp + c) = h;
    *(ushort8v*)(rLp + c) = l;
    *(ushort8v*)(Xnp + c) = xn;
  }
}

__global__ __launch_bounds__(256) void init_kernel(
    const float* __restrict__ x, const float* __restrict__ cb,
    unsigned short* __restrict__ Xnp, float* __restrict__ rnorm,
    unsigned short* __restrict__ rHp, unsigned short* __restrict__ rLp,
    float* __restrict__ cbn,
    unsigned short* __restrict__ cbHp, unsigned short* __restrict__ cbLp) {
  __shared__ float ldsNr[16 * 260];
  __shared__ float ssl[16];
  const int g = blockIdx.x;  // grid 2432
  if (g < 2048) {
    prep0_body(g, ldsNr, ssl, x, Xnp, rnorm, rHp, rLp);
    return;
  }
  if (g < 2304) {  // cbnorm: 256 blocks x 4 rows
    const int wave = threadIdx.x >> 6, lane = threadIdx.x & 63;
    const int e = (g - 2048) * 4 + wave;  // 0..NQ*NE-1
    float4 v = ((const float4*)(cb + (size_t)e * DIM))[lane];
    float ss = v.x * v.x + v.y * v.y + v.z * v.z + v.w * v.w;
#pragma unroll
    for (int m = 1; m < 64; m <<= 1) ss += __shfl_xor(ss, m, 64);
    if (lane == 0) cbn[e] = ss;
    return;
  }
  // cbsplit: 128 blocks x 256 chunks
  const int p = (g - 2304) * 256 + threadIdx.x;  // 32768 chunks
  const int stage = p >> 13, ps = p & 8191;
  const int l16 = ps & 15, quad = (ps >> 4) & 3, kf = (ps >> 6) & 7, et = ps >> 9;
  const int e = et * 16 + l16, k0 = kf * 32 + quad * 8;
  const float* src = cb + ((size_t)(stage * NE + e)) * DIM + k0;
  float4 v0 = ((const float4*)src)[0], v1 = ((const float4*)src)[1];
  float vv[8] = {v0.x, v0.y, v0.z, v0.w, v1.x, v1.y, v1.z, v1.w};
  ushort8v h, l;
#pragma unroll
  for (int i = 0; i < 8; ++i) {
    h[i] = f2bf(vv[i]); l[i] = f2bf(vv[i] - bf2f(h[i]));
  }
  *(ushort8v*)(cbHp + (size_t)p * 8) = h;
  *(ushort8v*)(cbLp + (size_t)p * 8) = l;
}

// ---------------- per-stage: gather xn[i1] (packed Qg) + pos, MERGED with
// lse_final of the previous stage (saves 3 launches/run).
// blocks 0..1023: gather for stage q, writes posCur.
// blocks 1024..1039: if q>0, lse for stage q-1 (reads ssum + posPrev, adds to
// acc[4+q-1]) then RE-ZEROES ssum in place for stage q's sim accumulation.
// pos is double-buffered so gather(q) writes never race lse(q-1) reads;
// ssum stage-0 zeroing is a one-time memset in kernel_launch.
__global__ __launch_bounds__(256) void gather_lse_kernel(
    const unsigned short* __restrict__ Xnp, const int* __restrict__ i1,
    const int* __restrict__ i2, unsigned short* __restrict__ Qgp,
    float* __restrict__ posCur, const float* __restrict__ posPrev,
    float* __restrict__ ssum, float* __restrict__ acc, int stage) {
  if (blockIdx.x >= 1024) {
    const int t = threadIdx.x;
    const int k = (blockIdx.x - 1024) * 256 + t;
    if (stage > 0) {
      float v = 10.0f + __logf(ssum[k]) - posPrev[k];
#pragma unroll
      for (int m = 1; m < 64; m <<= 1) v += __shfl_xor(v, m, 64);
      __shared__ float red[4];
      if ((t & 63) == 0) red[t >> 6] = v;
      __syncthreads();
      if (t == 0) atomicAdd(&acc[4 + stage - 1], red[0] + red[1] + red[2] + red[3]);
      ssum[k] = 0.0f;  // ready for this stage's sim
    }
    return;
  }
  const int wave = threadIdx.x >> 6, lane = threadIdx.x & 63;
  const int k = blockIdx.x * 4 + wave;
  const int a = i1[k], b = i2[k];
  const int j2 = lane >> 1, off = (lane & 1) * 4;
  ushort4 va = *(const ushort4*)(Xnp + chunkIdx(a, j2) * 8 + off);
  ushort4 vb = *(const ushort4*)(Xnp + chunkIdx(b, j2) * 8 + off);
  *(ushort4*)(Qgp + chunkIdx(k, j2) * 8 + off) = va;
  float d = bf2f(va.x) * bf2f(vb.x) + bf2f(va.y) * bf2f(vb.y) +
            bf2f(va.z) * bf2f(vb.z) + bf2f(va.w) * bf2f(vb.w);
#pragma unroll
  for (int m = 1; m < 64; m <<= 1) d += __shfl_xor(d, m, 64);
  if (lane == 0) posCur[k] = d * 10.0f;  // /TEMP
}

// ================== co-scheduled sim + (argmin+update) ==================
// Independent except Xnp (double-buffered: sim reads cur, tail writes next).
// 3072 blocks, blockIdx%3<2 -> sim (2048), %3==2 -> argmin+update (1024,
// 32 rows -- the r12 16-row split measured worse; the r14 LJF reorder was
// neutral, reverted to the simpler mod-3 map). The mod-3 interleave puts
// both kinds on every CU (3 coprime 8 XCDs); each fills the other's latency
// bubbles (fused 117us vs 134us serial). s_setprio(1) wraps sim's MFMA
// cluster (heterogeneous-blocks regime; 124->117us measured in r13).

__device__ __forceinline__ void sim_body(
    int sid, unsigned short* ldsB,
    const unsigned short* __restrict__ Qgp,
    const unsigned short* __restrict__ Xnp,
    float* __restrict__ s_sum) {
  const int tid  = threadIdx.x;
  const int lane = tid & 63;
  const int wave = tid >> 6;
  const int quad = lane >> 4;
  const int l16  = lane & 15;
  const int bx = sid & 31;   // q-tile group 0..31
  const int by = sid >> 5;   // n-chunk 0..63

  const int qt0  = bx * 8 + wave * 2;
  const int qbase = bx * 128 + wave * 32;

  short8 a[2][8];
#pragma unroll
  for (int t = 0; t < 2; ++t)
#pragma unroll
    for (int f = 0; f < 8; ++f)
      a[t][f] = *(const short8*)(Qgp + ((size_t)(((qt0 + t) * 8 + f) * 64 + lane)) * 8);

  float s[2][4] = {};
  const float C1 = 14.4269504088896341f;  // 10*log2(e); exp(10d-10)=exp2(d*C1-C1)
  const unsigned short* bsrc = Xnp + (size_t)(by * 32) * 4096;

  auto stageB = [&](int g) {
    const unsigned short* src = bsrc + (size_t)g * 4096 + wave * 1024 + lane * 8;
#pragma unroll
    for (int p = 0; p < 2; ++p)
      __builtin_amdgcn_global_load_lds(
          (const __attribute__((address_space(1))) unsigned int*)(src + p * 512),
          (__attribute__((address_space(3))) unsigned int*)(&ldsB[wave * 1024 + p * 512]),
          16, 0, 0);
  };

  stageB(0);
  for (int g = 0; g < 32; ++g) {
    asm volatile("s_waitcnt vmcnt(0)" ::: "memory");
    __builtin_amdgcn_s_barrier();
    __builtin_amdgcn_sched_barrier(0);
    short8 b[8];
#pragma unroll
    for (int f = 0; f < 8; ++f)
      b[f] = *(const short8*)(&ldsB[f * 512 + lane * 8]);
    asm volatile("s_waitcnt lgkmcnt(0)" ::: "memory");
    __builtin_amdgcn_s_barrier();
    __builtin_amdgcn_sched_barrier(0);
    if (g + 1 < 32) stageB(g + 1);

    f32x4 acc0[2] = {{0.f, 0.f, 0.f, 0.f}, {0.f, 0.f, 0.f, 0.f}};
    f32x4 acc1[2] = {{0.f, 0.f, 0.f, 0.f}, {0.f, 0.f, 0.f, 0.f}};
    __builtin_amdgcn_s_setprio(1);
#pragma unroll
    for (int f = 0; f < 4; ++f)
#pragma unroll
      for (int t = 0; t < 2; ++t) {
        acc0[t] = __builtin_amdgcn_mfma_f32_16x16x32_bf16(a[t][f], b[f], acc0[t], 0, 0, 0);
        acc1[t] = __builtin_amdgcn_mfma_f32_16x16x32_bf16(a[t][f + 4], b[f + 4], acc1[t], 0, 0, 0);
      }
    __builtin_amdgcn_s_setprio(0);
#pragma unroll
    for (int t = 0; t < 2; ++t) {
      f32x4 m = acc0[t] + acc1[t];
#pragma unroll
      for (int i = 0; i < 4; ++i)
        s[t][i] += fexp2(fmaf(m[i], C1, -C1));
    }
  }
#pragma unroll
  for (int m = 1; m < 16; m <<= 1)
#pragma unroll
    for (int t = 0; t < 2; ++t)
#pragma unroll
      for (int i = 0; i < 4; ++i) s[t][i] += __shfl_xor(s[t][i], m, 64);
  if (l16 == 0) {
#pragma unroll
    for (int t = 0; t < 2; ++t)
#pragma unroll
      for (int i = 0; i < 4; ++i)
        atomicAdd(&s_sum[qbase + t * 16 + quad * 4 + i], s[t][i]);
  }
}

// 32 rows/block (aid in [0,1024)); GEMM + top-2 + rescore + fused update tail.
__device__ __forceinline__ void argmin_update_body(
    int aid, char* smem,
    const float* __restrict__ xin, float* __restrict__ resid,
    const float* __restrict__ cb,
    const unsigned short* __restrict__ cbHp, const unsigned short* __restrict__ cbLp,
    const float* __restrict__ cbn, float* __restrict__ rnorm,
    unsigned short* __restrict__ rHp, unsigned short* __restrict__ rLp,
    unsigned short* __restrict__ XnpN,
    float* __restrict__ xq, float* __restrict__ idxf, float* __restrict__ acc,
    int stage) {
  float (*sV1)[32] = (float(*)[32])(smem);
  float (*sV2)[32] = (float(*)[32])(smem + 512);
  int   (*sIx)[32] = (int(*)[32])(smem + 1024);
  int*   sIdx      = (int*)(smem + 1536);
  int*   sFlag     = (int*)(smem + 1664);
  float* sred      = (float*)(smem + 1792);
  const int tid  = threadIdx.x;
  const int lane = tid & 63;
  const int wave = tid >> 6;
  const int quad = lane >> 4;
  const int l16  = lane & 15;
  const int rbase = aid * 32;
  const int t0 = aid * 2;
  const float* __restrict__ src = (stage == 0) ? xin : resid;

  f32x4 acc4[2][4];
#pragma unroll
  for (int rt = 0; rt < 2; ++rt)
#pragma unroll
    for (int ct = 0; ct < 4; ++ct) acc4[rt][ct] = (f32x4){0.f, 0.f, 0.f, 0.f};

  auto loadA = [&](int kf, short8 (&aH)[2], short8 (&aL)[2]) {
#pragma unroll
    for (int rt = 0; rt < 2; ++rt) {
      const size_t off = ((size_t)(((t0 + rt) * 8 + kf) * 64 + lane)) * 8;
      aH[rt] = *(const short8*)(rHp + off);
      aL[rt] = *(const short8*)(rLp + off);
    }
  };
  auto loadBc = [&](int kf, short8 (&bH)[4], short8 (&bL)[4]) {
#pragma unroll
    for (int ct = 0; ct < 4; ++ct) {
      const size_t boff = ((size_t)(((wave * 4 + ct) * 8 + kf) * 64 + lane)) * 8;
      bH[ct] = *(const short8*)(cbHp + boff);
      bL[ct] = *(const short8*)(cbLp + boff);
    }
  };
  auto computeK = [&](short8 (&aH)[2], short8 (&aL)[2], short8 (&bH)[4],
                      short8 (&bL)[4]) {
#pragma unroll
    for (int ct = 0; ct < 4; ++ct)
#pragma unroll
      for (int rt = 0; rt < 2; ++rt) {
        acc4[rt][ct] = __builtin_amdgcn_mfma_f32_16x16x32_bf16(aL[rt], bH[ct], acc4[rt][ct], 0, 0, 0);
        acc4[rt][ct] = __builtin_amdgcn_mfma_f32_16x16x32_bf16(aH[rt], bL[ct], acc4[rt][ct], 0, 0, 0);
        acc4[rt][ct] = __builtin_amdgcn_mfma_f32_16x16x32_bf16(aH[rt], bH[ct], acc4[rt][ct], 0, 0, 0);
      }
  };

  short8 aH0[2], aL0[2], bH0[4], bL0[4], aH1[2], aL1[2], bH1[4], bL1[4];
  loadA(0, aH0, aL0); loadBc(0, bH0, bL0);
  for (int kf = 0; kf < 8; kf += 2) {
    loadA(kf + 1, aH1, aL1); loadBc(kf + 1, bH1, bL1);
    computeK(aH0, aL0, bH0, bL0);
    if (kf + 2 < 8) { loadA(kf + 2, aH0, aL0); loadBc(kf + 2, bH0, bL0); }
    computeK(aH1, aL1, bH1, bL1);
  }

  // ---- epilogue: per-row top-2 over this wave's 64 e ----
  float cbe[4];
#pragma unroll
  for (int ct = 0; ct < 4; ++ct) cbe[ct] = cbn[(wave * 4 + ct) * 16 + l16];
#pragma unroll
  for (int rt = 0; rt < 2; ++rt) {
    float b1[4], b2[4]; int e1[4];
#pragma unroll
    for (int i = 0; i < 4; ++i) { b1[i] = 3.4e38f; b2[i] = 3.4e38f; e1[i] = 0; }
#pragma unroll
    for (int ct = 0; ct < 4; ++ct) {
      const int e = (wave * 4 + ct) * 16 + l16;
#pragma unroll
      for (int i = 0; i < 4; ++i) {
        const float v = fmaf(-2.0f, acc4[rt][ct][i], cbe[ct]);
        if (v < b1[i]) { b2[i] = b1[i]; b1[i] = v; e1[i] = e; }
        else if (v < b2[i]) b2[i] = v;
      }
    }
#pragma unroll
    for (int m = 1; m < 16; m <<= 1) {
#pragma unroll
      for (int i = 0; i < 4; ++i) {
        const float o1 = __shfl_xor(b1[i], m, 64);
        const float o2 = __shfl_xor(b2[i], m, 64);
        const int   oe = __shfl_xor(e1[i], m, 64);
        if (o1 < b1[i] || (o1 == b1[i] && oe < e1[i])) {
          b2[i] = fminf(b1[i], o2); b1[i] = o1; e1[i] = oe;
        } else {
          b2[i] = fminf(b2[i], o1);
        }
      }
    }
    if (l16 == 0) {
#pragma unroll
      for (int i = 0; i < 4; ++i) {
        const int r = rt * 16 + quad * 4 + i;
        sV1[wave][r] = b1[i]; sV2[wave][r] = b2[i]; sIx[wave][r] = e1[i];
      }
    }
  }
  __syncthreads();
  if (tid < 32) {
    float v1 = 3.4e38f, v2 = 3.4e38f; int ix = 0;
#pragma unroll
    for (int w = 0; w < 4; ++w) {
      const float a1 = sV1[w][tid], a2 = sV2[w][tid];
      const int ae = sIx[w][tid];
      if (a1 < v1) { v2 = fminf(v1, a2); v1 = a1; ix = ae; }
      else { v2 = fminf(v2, fminf(a1, a2)); }
    }
    sIdx[tid] = ix;
    sFlag[tid] = (v2 - v1 < RESCORE_MARGIN) ? 1 : 0;
  }
  __syncthreads();

  // ---- exact fp32 rescore for flagged rows (rare) ----
  for (int rr = 0; rr < 8; ++rr) {
    const int r = wave * 8 + rr;
    if (sFlag[r]) {
      const int row = rbase + r;
      const float* rrow = src + (size_t)row * DIM;
      float d[4] = {0.f, 0.f, 0.f, 0.f};
      for (int kb = 0; kb < 64; ++kb) {
        const float4 rv = ((const float4*)rrow)[kb];
#pragma unroll
        for (int j = 0; j < 4; ++j) {
          const float4 cv = ((const float4*)(cb + (size_t)(lane + 64 * j) * DIM))[kb];
          d[j] = fmaf(rv.x, cv.x, d[j]);
          d[j] = fmaf(rv.y, cv.y, d[j]);
          d[j] = fmaf(rv.z, cv.z, d[j]);
          d[j] = fmaf(rv.w, cv.w, d[j]);
        }
      }
      const float rn = rnorm[row];
      float bv = 3.4e38f; int be = 0;
#pragma unroll
      for (int j = 0; j < 4; ++j) {
        const int e = lane + 64 * j;
        const float v = (rn - 2.0f * d[j]) + cbn[e];
        if (v < bv) { bv = v; be = e; }
      }
#pragma unroll
      for (int m = 1; m < 64; m <<= 1) {
        const float vo = __shfl_xor(bv, m, 64);
        const int   eo = __shfl_xor(be, m, 64);
        if (vo < bv || (vo == bv && eo < be)) { bv = vo; be = eo; }
      }
      if (lane == 0) sIdx[r] = be;
    }
  }
  __syncthreads();

  // ---- fused update tail: 2 rows/wave x 4 passes (r8 structure) ----
  const int half = lane >> 5, j = lane & 31;
  float msum = 0.0f;
  for (int i = 0; i < 4; ++i) {
    const int rr = i * 8 + wave * 2 + half;
    const int row = rbase + rr;
    const int e = sIdx[rr];
    const float4* rp = (const float4*)(src + (size_t)row * DIM + j * 8);
    float4 r0 = rp[0], r1 = rp[1];
    const float4* qp = (const float4*)(cb + (size_t)e * DIM + j * 8);
    float4 q0 = qp[0], q1 = qp[1];
    float nr[8] = {r0.x - q0.x, r0.y - q0.y, r0.z - q0.z, r0.w - q0.w,
                   r1.x - q1.x, r1.y - q1.y, r1.z - q1.z, r1.w - q1.w};
    float ss = 0.f;
#pragma unroll
    for (int u = 0; u < 8; ++u) ss += nr[u] * nr[u];
    if (stage == 3) {
      // x_q = x - resid_final (xq never accumulated)
      const float4* xr = (const float4*)(xin + (size_t)row * DIM + j * 8);
      float4 x0 = xr[0], x1 = xr[1];
      float4* xp = (float4*)(xq + (size_t)row * DIM + j * 8);
      xp[0] = (float4){x0.x - nr[0], x0.y - nr[1], x0.z - nr[2], x0.w - nr[3]};
      xp[1] = (float4){x1.x - nr[4], x1.y - nr[5], x1.z - nr[6], x1.w - nr[7]};
    }
#pragma unroll
    for (int m = 1; m < 32; m <<= 1) ss += __shfl_xor(ss, m, 64);
    if (stage < 3) {
      float4* rw = (float4*)(resid + (size_t)row * DIM + j * 8);
      rw[0] = (float4){nr[0], nr[1], nr[2], nr[3]};
      rw[1] = (float4){nr[4], nr[5], nr[6], nr[7]};
      const float sc = rsqrtf(ss + 1e-12f);
      ushort8v h, l, xn;
#pragma unroll
      for (int u = 0; u < 8; ++u) {
        h[u] = f2bf(nr[u]); l[u] = f2bf(nr[u] - bf2f(h[u])); xn[u] = f2bf(nr[u] * sc);
      }
      const size_t c = chunkIdx(row, j) * 8;
      *(ushort8v*)(rHp + c) = h;
      *(ushort8v*)(rLp + c) = l;
      *(ushort8v*)(XnpN + c) = xn;   // NEXT-stage buffer (sim reads cur)
      if (j == 0) rnorm[row] = ss;
    }
    if (j == 0) {
      idxf[(size_t)row * NQ + stage] = (float)e;
      msum += ss;
    }
  }
  msum += __shfl_xor(msum, 32, 64);
  if (lane == 0) sred[wave] = msum;
  __syncthreads();
  if (tid == 0) atomicAdd(&acc[0], sred[0] + sred[1] + sred[2] + sred[3]);
}

__global__ __launch_bounds__(256, 2) void sim_argmin_kernel(
    const unsigned short* __restrict__ Qgp, const unsigned short* __restrict__ Xnp,
    float* __restrict__ s_sum,
    const float* __restrict__ xin, float* __restrict__ resid,
    const float* __restrict__ cb,
    const unsigned short* __restrict__ cbHp, const unsigned short* __restrict__ cbLp,
    const float* __restrict__ cbn, float* __restrict__ rnorm,
    unsigned short* __restrict__ rHp, unsigned short* __restrict__ rLp,
    unsigned short* __restrict__ XnpN,
    float* __restrict__ xq, float* __restrict__ idxf, float* __restrict__ acc,
    int stage) {
  __shared__ unsigned short smem[4096];  // 8KB: sim B-buffer / argmin scratch
  const int g = blockIdx.x;              // grid 3072
  const int q3 = g / 3, r3 = g - q3 * 3;
  if (r3 < 2) {
    sim_body(q3 * 2 + r3, smem, Qgp, Xnp, s_sum);
  } else {
    argmin_update_body(q3, (char*)smem, xin, resid, cb, cbHp, cbLp, cbn,
                       rnorm, rHp, rLp, XnpN, xq, idxf, acc, stage);
  }
}

// ---------------- last stage lse -> outer loss accumulator ----------------
__global__ __launch_bounds__(256) void lse_final_kernel(
    const float* __restrict__ s_sum, const float* __restrict__ pos,
    float* __restrict__ acc, int stage) {
  const int t = threadIdx.x;
  const int k = blockIdx.x * 256 + t;
  float v = 10.0f + __logf(s_sum[k]) - pos[k];
#pragma unroll
  for (int m = 1; m < 64; m <<= 1) v += __shfl_xor(v, m, 64);
  __shared__ float red[4];
  if ((t & 63) == 0) red[t >> 6] = v;
  __syncthreads();
  if (t == 0) atomicAdd(&acc[4 + stage], red[0] + red[1] + red[2] + red[3]);
}

// ---------------- finalize scalar outputs ----------------
__global__ void finalize_kernel(const float* __restrict__ acc, float* __restrict__ out) {
  const int t = threadIdx.x;
  if (t == 0) out[ND] = acc[0] * (1.25f / (4.0f * (float)ND));
  if (t < 4) out[ND + 1 + t] = acc[4 + t] * (1.0f / (float)KP);
}

extern "C" void kernel_launch(void* const* d_in, const int* in_sizes, int n_in,
                              void* d_out, int out_size, void* d_ws, size_t ws_size,
                              hipStream_t stream) {
  const float* x         = (const float*)d_in[0];
  const float* codebooks = (const float*)d_in[1];
  const int*   i1        = (const int*)d_in[2];
  const int*   i2        = (const int*)d_in[3];
  float* out = (float*)d_out;
  float* out_xq   = out;                 // [N, D]
  float* out_idxf = out + ND + 1 + NQ;   // [N, NQ] as float

  char* w = (char*)d_ws;
  float*          resid = (float*)w;          w += (size_t)N_ROWS * DIM * 4;
  unsigned short* XnpA  = (unsigned short*)w; w += (size_t)N_ROWS * DIM * 2;
  unsigned short* XnpB  = (unsigned short*)w; w += (size_t)N_ROWS * DIM * 2;
  unsigned short* rHp   = (unsigned short*)w; w += (size_t)N_ROWS * DIM * 2;
  unsigned short* rLp   = (unsigned short*)w; w += (size_t)N_ROWS * DIM * 2;
  float*          rnorm = (float*)w;          w += (size_t)N_ROWS * 4;
  unsigned short* Qgp   = (unsigned short*)w; w += (size_t)KP * DIM * 2;
  float*          posA  = (float*)w;          w += (size_t)KP * 4;
  float*          posB  = (float*)w;          w += (size_t)KP * 4;
  float*          ssum  = (float*)w;          w += (size_t)KP * 4;
  float*          cbn   = (float*)w;          w += (size_t)NQ * NE * 4;
  unsigned short* cbHp  = (unsigned short*)w; w += (size_t)NQ * NE * DIM * 2;
  unsigned short* cbLp  = (unsigned short*)w; w += (size_t)NQ * NE * DIM * 2;
  float*          acc   = (float*)w;          w += 32;  // [0]=sumsq, [4..7]=outer sums

  // fused init: prep0 | cbnorm | cbsplit (mutually independent)
  init_kernel<<<2432, 256, 0, stream>>>(x, codebooks, XnpA, rnorm, rHp, rLp,
                                        cbn, cbHp, cbLp);
  hipMemsetAsync(acc, 0, 32, stream);
  hipMemsetAsync(ssum, 0, (size_t)KP * 4, stream);  // stage-0 zero; later
                                                    // stages re-zeroed by lse
  unsigned short* XnpCur = XnpA;
  unsigned short* XnpNxt = XnpB;
  float* pbuf[2] = {posA, posB};
  for (int q = 0; q < NQ; ++q) {
    const float* cb = codebooks + (size_t)q * NE * DIM;
    // gather(q) + lse(q-1); pos double-buffered (gather writes pbuf[q&1],
    // lse reads pbuf[(q-1)&1]); lse re-zeroes ssum after reading.
    gather_lse_kernel<<<1040, 256, 0, stream>>>(
        XnpCur, i1, i2, Qgp, pbuf[q & 1], pbuf[(q + 1) & 1], ssum, acc, q);
    sim_argmin_kernel<<<3072, 256, 0, stream>>>(
        Qgp, XnpCur, ssum, x, resid, cb,
        cbHp + (size_t)q * NE * DIM, cbLp + (size_t)q * NE * DIM,
        cbn + q * NE, rnorm, rHp, rLp, XnpNxt, out_xq, out_idxf, acc, q);
    unsigned short* tmp = XnpCur; XnpCur = XnpNxt; XnpNxt = tmp;
  }
  lse_final_kernel<<<16, 256, 0, stream>>>(ssum, pbuf[3 & 1], acc, 3);
  finalize_kernel<<<1, 64, 0, stream>>>(acc, out);
}